// Round 5
// baseline (671.449 us; speedup 1.0000x reference)
//
#include <hip/hip_runtime.h>
#include <hip/hip_bf16.h>
#include <stdint.h>

using bf16 = __hip_bfloat16;
typedef __bf16 bf16x8 __attribute__((ext_vector_type(8)));
typedef float  f32x4  __attribute__((ext_vector_type(4)));

#define TOKENS 16384
#define DMODEL 1024
#define DFF    4096

// ---------------------------------------------------------------------------
// async global->LDS, 16B per lane. LDS dest = wave-uniform base + lane*16.
// ---------------------------------------------------------------------------
__device__ __forceinline__ void gload_lds16(const void* gptr, void* lptr) {
  __builtin_amdgcn_global_load_lds(
      (const __attribute__((address_space(1))) uint32_t*)gptr,
      (__attribute__((address_space(3))) uint32_t*)lptr,
      16, 0, 0);
}

__device__ __forceinline__ float bfraw2f(unsigned short u) {
  union { unsigned int i; float f; } x;
  x.i = ((unsigned int)u) << 16;
  return x.f;
}

__device__ __forceinline__ unsigned short f2bfraw(float f) {
  union { float f; unsigned int i; } x;
  x.f = f;
  unsigned int lsb = (x.i >> 16) & 1;
  return (unsigned short)((x.i + 0x7fff + lsb) >> 16);  // RNE (finite inputs)
}

// ---------------------------------------------------------------------------
// f32 -> bf16 elementwise convert (x). One float4 per thread.
// ---------------------------------------------------------------------------
__global__ __launch_bounds__(256) void cvt_f32_bf16(
    const float* __restrict__ in, bf16* __restrict__ out, int n4) {
  const int i = blockIdx.x * 256 + threadIdx.x;
  if (i >= n4) return;
  const float4 v = reinterpret_cast<const float4*>(in)[i];
  bf16 o[4] = {__float2bfloat16(v.x), __float2bfloat16(v.y),
               __float2bfloat16(v.z), __float2bfloat16(v.w)};
  reinterpret_cast<uint2*>(out)[i] = *reinterpret_cast<const uint2*>(o);
}

// ---------------------------------------------------------------------------
// Tiled transpose + convert: in[R][C] (f32) -> out[C][R] (bf16).
// ---------------------------------------------------------------------------
__global__ __launch_bounds__(256) void transpose_f32_bf16(
    const float* __restrict__ in, bf16* __restrict__ out, int R, int C) {
  __shared__ float tile[32][33];
  const int bx = blockIdx.x * 32;
  const int by = blockIdx.y * 32;
  const int tx = threadIdx.x;
  const int ty = threadIdx.y;
#pragma unroll
  for (int i = 0; i < 32; i += 8)
    tile[ty + i][tx] = in[(size_t)(by + ty + i) * C + (bx + tx)];
  __syncthreads();
#pragma unroll
  for (int i = 0; i < 32; i += 8)
    out[(size_t)(bx + ty + i) * R + (by + tx)] =
        __float2bfloat16(tile[tx][ty + i]);
}

// ---------------------------------------------------------------------------
// 256x256 8-phase GEMM, SINGLE barrier per phase.
// C[M,N] = A[M,K] * B[K,N], A row-major bf16, Bt = B^T [N,K] bf16.
// 512 threads = 8 waves (2M x 4N); per wave 128x64 output; BK=64.
// Phase structure: {ds_reads | 1 half-tile stage (2 gload_lds) | [vmcnt]} ->
// BAR -> setprio(1) 16 MFMA setprio(0).  NO trailing barrier: waves skew so
// one wave's next-phase ds_reads overlap its SIMD-partner's MFMA cluster
// (rounds 3/4 showed read-count reduction is flat -- the segments were
// strictly serialized by the 2nd barrier; this removes the serialization).
// Hazard ledger (single-barrier): every region's last ds_read is issued
// >=1 barrier before the stage that overwrites it (A00: read P1 pre-BAR(P1),
// staged P3 post-BAR(P2); B00: read P3, staged P4 post-BAR(P3); etc.), and
// read completion precedes each wave's next barrier via the compiler's
// lgkmcnt before the consuming MFMAs. vmcnt ledger is program-order and
// unchanged: vmcnt(4) at P4/P8 retires exactly the regions consumed in the
// next 4 phases. A-quad af[4][2] pair-shared (read at odd phases); B-quads
// read per-phase (48 live operand regs -- the known spill-free budget).
// epi: 0=+bias; 1=+bias,relu; 2=+bias+resf(f32); 3=+bias+resb(bf16)
// ---------------------------------------------------------------------------
__device__ __forceinline__ bf16x8 ldsfrag(const bf16* region, int lrow, int cb) {
  return *reinterpret_cast<const bf16x8*>(
      region + lrow * 64 + (((cb) ^ ((lrow & 7) << 4)) >> 1));
}

__device__ __forceinline__ void read_afrag(
    bf16x8 (&af)[4][2], const bf16* Ar, int wm, int lane) {
  const int lr = lane & 15, cb0 = (lane >> 4) * 16;
#pragma unroll
  for (int mi = 0; mi < 4; ++mi)
#pragma unroll
    for (int ks = 0; ks < 2; ++ks)
      af[mi][ks] = ldsfrag(Ar, wm * 64 + mi * 16 + lr, ks * 64 + cb0);
}

__device__ __forceinline__ void read_bfrag(
    bf16x8 (&bq)[2][2], const bf16* Br, int wn, int lane) {
  const int lr = lane & 15, cb0 = (lane >> 4) * 16;
#pragma unroll
  for (int ni = 0; ni < 2; ++ni)
#pragma unroll
    for (int ks = 0; ks < 2; ++ks)
      bq[ni][ks] = ldsfrag(Br, wn * 32 + ni * 16 + lr, ks * 64 + cb0);
}

template <int MQ, int NQ, int WAIT, bool READ_A>
__device__ __forceinline__ void phase_op(
    f32x4 (&acc)[8][4], bf16x8 (&af)[4][2], const bf16* Ar, const bf16* Br,
    const int wm, const int wn, const int lane,
    const bf16* g0, bf16* l0, const bf16* g1, bf16* l1) {
  if constexpr (READ_A) read_afrag(af, Ar, wm, lane);
  bf16x8 bq[2][2];
  read_bfrag(bq, Br, wn, lane);
  if (g0 != nullptr) { gload_lds16(g0, l0); gload_lds16(g1, l1); }
  if constexpr (WAIT == 4) asm volatile("s_waitcnt vmcnt(4)" ::: "memory");
  if constexpr (WAIT == 0) asm volatile("s_waitcnt vmcnt(0)" ::: "memory");
  asm volatile("s_barrier" ::: "memory");
  __builtin_amdgcn_s_setprio(1);
#pragma unroll
  for (int mi = 0; mi < 4; ++mi)
#pragma unroll
    for (int ni = 0; ni < 2; ++ni)
#pragma unroll
      for (int ks = 0; ks < 2; ++ks)
        acc[MQ * 4 + mi][NQ * 2 + ni] = __builtin_amdgcn_mfma_f32_16x16x32_bf16(
            bq[ni][ks], af[mi][ks], acc[MQ * 4 + mi][NQ * 2 + ni], 0, 0, 0);
  __builtin_amdgcn_s_setprio(0);
  // no trailing barrier: next phase's reads may overlap other waves' MFMAs
}

// stage macros: (tile, half, LDS-region) -> 4 args (gsrc0,ldst0,gsrc1,ldst1)
#define STG_A(tile, h, dst)                                  \
  Ab + offA[h][0] + (size_t)(tile) * 64, (dst) + oe0,        \
  Ab + offA[h][1] + (size_t)(tile) * 64, (dst) + oe1
#define STG_B(tile, q, dst)                                  \
  Bt + offB[q][0] + (size_t)(tile) * 64, (dst) + oe0,        \
  Bt + offB[q][1] + (size_t)(tile) * 64, (dst) + oe1
#define STG_NONE \
  (const bf16*)nullptr, (bf16*)nullptr, (const bf16*)nullptr, (bf16*)nullptr

__global__ __launch_bounds__(512, 2) void gemm256(
    const bf16* __restrict__ Ab, const bf16* __restrict__ Bt,
    const float* __restrict__ bias, const float* __restrict__ resf,
    const bf16* __restrict__ resb, bf16* __restrict__ outb,
    const int M, const int N, const int K, const int epi) {
  union SMem {
    struct { bf16 A[2][2][8192]; bf16 B[2][2][8192]; } p;  // 128 KiB
    bf16 C[256 * 256];                                     // 128 KiB
  };
  __shared__ alignas(16) SMem sm;

  const int t    = threadIdx.x;
  const int wave = t >> 6;
  const int lane = t & 63;
  const int wm = wave >> 2;   // 0..1  (M wave index, 128 rows each)
  const int wn = wave & 3;    // 0..3  (N wave index, 64 cols each)

  // XCD-aware bijective swizzle (all grids here have nwg % 8 == 0)
  const int gx  = gridDim.x;
  const int nwg = gx * (int)gridDim.y;
  const int bid = (int)blockIdx.y * gx + (int)blockIdx.x;
  const int cpx = nwg >> 3;
  const int swz = (bid & 7) * cpx + (bid >> 3);
  const int m_base = (swz / gx) * 256;
  const int n_base = (swz % gx) * 256;

  // staging source offsets (pre-swizzled global columns so gload_lds' linear
  // LDS writes land XOR-swizzled; readers apply the same XOR)
  const int tr8 = t >> 3;                                // 0..63
  const int ksw = ((t & 7) * 8) ^ ((tr8 & 7) * 8);       // swizzled k within BK
  uint32_t offA[2][2], offB[2][2];                       // [half][L]
#pragma unroll
  for (int h = 0; h < 2; ++h)
#pragma unroll
    for (int L = 0; L < 2; ++L) {
      offA[h][L] =
          (uint32_t)(m_base + L * 128 + h * 64 + tr8) * (uint32_t)K + ksw;
      offB[h][L] =
          (uint32_t)(n_base + (L * 2 + (t >> 8)) * 64 + h * 32 + (tr8 & 31)) *
              (uint32_t)K + ksw;
    }
  const int oe0 = t * 8;         // LDS element offset, load L=0
  const int oe1 = 4096 + t * 8;  // load L=1

  bf16* const A00 = sm.p.A[0][0]; bf16* const A01 = sm.p.A[0][1];
  bf16* const A10 = sm.p.A[1][0]; bf16* const A11 = sm.p.A[1][1];
  bf16* const B00 = sm.p.B[0][0]; bf16* const B01 = sm.p.B[0][1];
  bf16* const B10 = sm.p.B[1][0]; bf16* const B11 = sm.p.B[1][1];

  f32x4 acc[8][4] = {};
  bf16x8 af[4][2];  // pair-shared A fragment file (read at odd phases)

  // prologue: T0 {A0,B0,A1,B1} (buf0) + T1 {A0,B0} (buf1) = 12 loads;
  // vmcnt(4) retires all of T0, leaves T1.A0/B0 in flight.
  gload_lds16(Ab + offA[0][0], A00 + oe0);
  gload_lds16(Ab + offA[0][1], A00 + oe1);
  gload_lds16(Bt + offB[0][0], B00 + oe0);
  gload_lds16(Bt + offB[0][1], B00 + oe1);
  gload_lds16(Ab + offA[1][0], A01 + oe0);
  gload_lds16(Ab + offA[1][1], A01 + oe1);
  gload_lds16(Bt + offB[1][0], B01 + oe0);
  gload_lds16(Bt + offB[1][1], B01 + oe1);
  gload_lds16(Ab + offA[0][0] + 64, A10 + oe0);
  gload_lds16(Ab + offA[0][1] + 64, A10 + oe1);
  gload_lds16(Bt + offB[0][0] + 64, B10 + oe0);
  gload_lds16(Bt + offB[0][1] + 64, B10 + oe1);
  asm volatile("s_waitcnt vmcnt(4)" ::: "memory");
  asm volatile("s_barrier" ::: "memory");

  // main loop: iteration computes tiles T=2i (buf0, P1-4) and T+1 (buf1, P5-8)
  // stage ledger (region is dead when staged; waits retire the needed tile):
  //  P1:(T+1).A1->A11  P2:(T+1).B1->B11  P3:(T+2).A0->A00  P4:(T+2).B0->B00 +vmcnt(4)
  //  P5:(T+2).A1->A01  P6:(T+2).B1->B01  P7:(T+3).A0->A10  P8:(T+3).B0->B10 +vmcnt(4)
  const int niter = K >> 7;  // K/128
  for (int i = 0; i < niter - 1; ++i) {
    const int T = 2 * i;
    phase_op<0, 0, -1, true >(acc, af, A00, B00, wm, wn, lane, STG_A(T + 1, 1, A11));
    phase_op<0, 1, -1, false>(acc, af, A00, B01, wm, wn, lane, STG_B(T + 1, 1, B11));
    phase_op<1, 0, -1, true >(acc, af, A01, B00, wm, wn, lane, STG_A(T + 2, 0, A00));
    phase_op<1, 1,  4, false>(acc, af, A01, B01, wm, wn, lane, STG_B(T + 2, 0, B00));
    phase_op<0, 0, -1, true >(acc, af, A10, B10, wm, wn, lane, STG_A(T + 2, 1, A01));
    phase_op<0, 1, -1, false>(acc, af, A10, B11, wm, wn, lane, STG_B(T + 2, 1, B01));
    phase_op<1, 0, -1, true >(acc, af, A11, B10, wm, wn, lane, STG_A(T + 3, 0, A10));
    phase_op<1, 1,  4, false>(acc, af, A11, B11, wm, wn, lane, STG_B(T + 3, 0, B10));
  }
  {  // last iteration: finish staging T+1, drain at P4, no further prefetch
    const int T = 2 * (niter - 1);
    phase_op<0, 0, -1, true >(acc, af, A00, B00, wm, wn, lane, STG_A(T + 1, 1, A11));
    phase_op<0, 1, -1, false>(acc, af, A00, B01, wm, wn, lane, STG_B(T + 1, 1, B11));
    phase_op<1, 0, -1, true >(acc, af, A01, B00, wm, wn, lane, STG_NONE);
    phase_op<1, 1,  0, false>(acc, af, A01, B01, wm, wn, lane, STG_NONE);
    phase_op<0, 0, -1, true >(acc, af, A10, B10, wm, wn, lane, STG_NONE);
    phase_op<0, 1, -1, false>(acc, af, A10, B11, wm, wn, lane, STG_NONE);
    phase_op<1, 0, -1, true >(acc, af, A11, B10, wm, wn, lane, STG_NONE);
    phase_op<1, 1, -1, false>(acc, af, A11, B11, wm, wn, lane, STG_NONE);
  }

  __syncthreads();  // full drain; LDS now reused as swizzled C-stage

  // stage C tile (bias/relu in-register), XOR-swizzled cols (stride 256)
  const int lr = lane & 15;
  const int g4 = lane >> 4;
#pragma unroll
  for (int nj = 0; nj < 4; ++nj) {
    const int cb = wn * 64 + nj * 16 + g4 * 4;
    const float4 bv4 = *reinterpret_cast<const float4*>(&bias[n_base + cb]);
#pragma unroll
    for (int mi = 0; mi < 8; ++mi) {
      const int row = wm * 128 + mi * 16 + lr;
      const f32x4 a = acc[mi][nj];
      float v0 = a[0] + bv4.x, v1 = a[1] + bv4.y;
      float v2 = a[2] + bv4.z, v3 = a[3] + bv4.w;
      if (epi == 1) {
        v0 = fmaxf(v0, 0.f); v1 = fmaxf(v1, 0.f);
        v2 = fmaxf(v2, 0.f); v3 = fmaxf(v3, 0.f);
      }
      ushort4 pk = {f2bfraw(v0), f2bfraw(v1), f2bfraw(v2), f2bfraw(v3)};
      *reinterpret_cast<ushort4*>(
          &sm.C[row * 256 + (cb ^ ((row & 7) << 3))]) = pk;
    }
  }
  __syncthreads();

  // coalesced flush: 16 rows/pass, 16B per lane (512B per row)
#pragma unroll
  for (int pass = 0; pass < 16; ++pass) {
    const int row = pass * 16 + (t >> 5);
    const int fce = (t & 31) * 8;
    const uint4 raw = *reinterpret_cast<const uint4*>(
        &sm.C[row * 256 + (fce ^ ((row & 7) << 3))]);
    const size_t gidx = (size_t)(m_base + row) * N + n_base + fce;
    if (epi <= 1) {
      *reinterpret_cast<uint4*>(&outb[gidx]) = raw;
    } else {
      const unsigned short* u = reinterpret_cast<const unsigned short*>(&raw);
      float v[8];
#pragma unroll
      for (int j = 0; j < 8; ++j) v[j] = bfraw2f(u[j]);
      if (epi == 2) {
        const float4 r0 = *reinterpret_cast<const float4*>(&resf[gidx]);
        const float4 r1 = *reinterpret_cast<const float4*>(&resf[gidx + 4]);
        v[0] += r0.x; v[1] += r0.y; v[2] += r0.z; v[3] += r0.w;
        v[4] += r1.x; v[5] += r1.y; v[6] += r1.z; v[7] += r1.w;
      } else {
        const uint4 rb = *reinterpret_cast<const uint4*>(&resb[gidx]);
        const unsigned short* ru = reinterpret_cast<const unsigned short*>(&rb);
#pragma unroll
        for (int j = 0; j < 8; ++j) v[j] += bfraw2f(ru[j]);
      }
      ushort4 lo = {f2bfraw(v[0]), f2bfraw(v[1]), f2bfraw(v[2]), f2bfraw(v[3])};
      ushort4 hi = {f2bfraw(v[4]), f2bfraw(v[5]), f2bfraw(v[6]), f2bfraw(v[7])};
      uint4 o;
      o.x = *reinterpret_cast<const uint32_t*>(&lo.x);
      o.y = *reinterpret_cast<const uint32_t*>(&lo.z);
      o.z = *reinterpret_cast<const uint32_t*>(&hi.x);
      o.w = *reinterpret_cast<const uint32_t*>(&hi.z);
      *reinterpret_cast<uint4*>(&outb[gidx]) = o;
    }
  }
}

// ---------------------------------------------------------------------------
// Per-token head-mixing attention. One 256-thread block per token.
// ---------------------------------------------------------------------------
__global__ __launch_bounds__(256) void attn_kernel(
    const bf16* __restrict__ qkv, bf16* __restrict__ ctx) {
  __shared__ float q[16][65], kk[16][65], vv[16][65];
  __shared__ float sc[16][17], pw[16][17];
  const int tok = blockIdx.x;
  const int t   = threadIdx.x;

  const ushort2* base2 =
      reinterpret_cast<const ushort2*>(qkv + (size_t)tok * 3072);
#pragma unroll
  for (int e2 = t; e2 < 1536; e2 += 256) {
    const ushort2 u = base2[e2];
    const int e = e2 * 2;
    const int h = e / 192;
    const int rem = e - h * 192;
    const int which = rem >> 6;
    const int d = rem & 63;
    const float f0 = bfraw2f(u.x), f1 = bfraw2f(u.y);
    if (which == 0)      { q[h][d] = f0;  q[h][d + 1] = f1; }
    else if (which == 1) { kk[h][d] = f0; kk[h][d + 1] = f1; }
    else                 { vv[h][d] = f0; vv[h][d + 1] = f1; }
  }
  __syncthreads();

  const int h = t >> 4, g = t & 15;
  float s = 0.f;
#pragma unroll
  for (int d = 0; d < 64; ++d) s += q[h][d] * kk[g][d];
  s *= 0.125f;
  sc[h][g] = s;
  __syncthreads();

  float mx = sc[h][0];
#pragma unroll
  for (int j = 1; j < 16; ++j) mx = fmaxf(mx, sc[h][j]);
  float sum = 0.f;
#pragma unroll
  for (int j = 0; j < 16; ++j) sum += __expf(sc[h][j] - mx);
  pw[h][g] = __expf(s - mx) / sum;
  __syncthreads();

  const int d0 = (t & 15) * 4;
  float c0 = 0.f, c1 = 0.f, c2 = 0.f, c3 = 0.f;
#pragma unroll
  for (int j = 0; j < 16; ++j) {
    const float w = pw[h][j];
    c0 += w * vv[j][d0 + 0];
    c1 += w * vv[j][d0 + 1];
    c2 += w * vv[j][d0 + 2];
    c3 += w * vv[j][d0 + 3];
  }
  bf16 o[4] = {__float2bfloat16(c0), __float2bfloat16(c1),
               __float2bfloat16(c2), __float2bfloat16(c3)};
  *reinterpret_cast<uint2*>(ctx + (size_t)tok * 1024 + t * 4) =
      *reinterpret_cast<const uint2*>(o);
}

// ---------------------------------------------------------------------------
// LayerNorm over 1024, bf16 input, f32 gamma/beta.
// ---------------------------------------------------------------------------
__global__ __launch_bounds__(256) void ln_kernel(
    const bf16* __restrict__ y, const float* __restrict__ gamma,
    const float* __restrict__ beta, bf16* __restrict__ outb,
    float* __restrict__ outf) {
  const int row = blockIdx.x;
  const int t = threadIdx.x;
  const uint2 raw =
      reinterpret_cast<const uint2*>(y + (size_t)row * 1024)[t];
  float f0 = bfraw2f((unsigned short)(raw.x & 0xffff));
  float f1 = bfraw2f((unsigned short)(raw.x >> 16));
  float f2 = bfraw2f((unsigned short)(raw.y & 0xffff));
  float f3 = bfraw2f((unsigned short)(raw.y >> 16));
  float s  = f0 + f1 + f2 + f3;
  float ss = f0 * f0 + f1 * f1 + f2 * f2 + f3 * f3;
#pragma unroll
  for (int off = 32; off > 0; off >>= 1) {
    s  += __shfl_down(s, off);
    ss += __shfl_down(ss, off);
  }
  __shared__ float red[8];
  const int wave = t >> 6, lane = t & 63;
  if (lane == 0) { red[wave] = s; red[wave + 4] = ss; }
  __syncthreads();
  s  = red[0] + red[1] + red[2] + red[3];
  ss = red[4] + red[5] + red[6] + red[7];
  const float mu  = s * (1.0f / 1024.0f);
  const float var = ss * (1.0f / 1024.0f) - mu * mu;
  const float inv = rsqrtf(var + 1e-5f);
  const int c = t * 4;
  const float r0 = (f0 - mu) * inv * gamma[c + 0] + beta[c + 0];
  const float r1 = (f1 - mu) * inv * gamma[c + 1] + beta[c + 1];
  const float r2 = (f2 - mu) * inv * gamma[c + 2] + beta[c + 2];
  const float r3 = (f3 - mu) * inv * gamma[c + 3] + beta[c + 3];
  if (outf != nullptr) {
    float4 o4 = {r0, r1, r2, r3};
    reinterpret_cast<float4*>(outf + (size_t)row * 1024)[t] = o4;
  } else {
    bf16 o[4] = {__float2bfloat16(r0), __float2bfloat16(r1),
                 __float2bfloat16(r2), __float2bfloat16(r3)};
    *reinterpret_cast<uint2*>(outb + (size_t)row * 1024 + c) =
        *reinterpret_cast<const uint2*>(o);
  }
}

// ---------------------------------------------------------------------------
extern "C" void kernel_launch(void* const* d_in, const int* in_sizes, int n_in,
                              void* d_out, int out_size, void* d_ws, size_t ws_size,
                              hipStream_t stream) {
  const float* x    = (const float*)d_in[0];
  const float* Wqkv = (const float*)d_in[1];
  const float* bqkv = (const float*)d_in[2];
  const float* Wo   = (const float*)d_in[3];
  const float* bo   = (const float*)d_in[4];
  const float* W1   = (const float*)d_in[5];
  const float* b1   = (const float*)d_in[6];
  const float* W2   = (const float*)d_in[7];
  const float* b2   = (const float*)d_in[8];
  const float* g1   = (const float*)d_in[9];
  const float* be1  = (const float*)d_in[10];
  const float* g2   = (const float*)d_in[11];
  const float* be2  = (const float*)d_in[12];
  float* out = (float*)d_out;

  // Workspace layout (overlays annotated). Total ~226 MB.
  char* p = (char*)d_ws;
  bf16* regA  = (bf16*)p;  p += (size_t)TOKENS * 1024 * 2;
  bf16* qkvb  = (bf16*)p;
  bf16* hbuf  = qkvb;
  p += (size_t)TOKENS * 3072 * 2;
  bf16* ybufb = (bf16*)p;  p += (size_t)TOKENS * 1024 * 2;
  bf16* x1b   = (bf16*)p;  p += (size_t)TOKENS * 1024 * 2;
  bf16* WqkvT = (bf16*)p;  p += (size_t)3072 * 1024 * 2;
  bf16* WoT   = (bf16*)p;  p += (size_t)1024 * 1024 * 2;
  bf16* W1T   = (bf16*)p;  p += (size_t)4096 * 1024 * 2;
  bf16* W2T   = (bf16*)p;  p += (size_t)1024 * 4096 * 2;

  bf16* xb  = regA;
  bf16* ctx = regA;
  bf16* y2b = regA;

  cvt_f32_bf16<<<(TOKENS * 1024 / 4 + 255) / 256, 256, 0, stream>>>(
      x, xb, TOKENS * 1024 / 4);

  const dim3 tb(32, 8);
  transpose_f32_bf16<<<dim3(3072 / 32, 1024 / 32), tb, 0, stream>>>(Wqkv, WqkvT, 1024, 3072);
  transpose_f32_bf16<<<dim3(1024 / 32, 1024 / 32), tb, 0, stream>>>(Wo,   WoT,   1024, 1024);
  transpose_f32_bf16<<<dim3(4096 / 32, 1024 / 32), tb, 0, stream>>>(W1,   W1T,   1024, 4096);
  transpose_f32_bf16<<<dim3(1024 / 32, 4096 / 32), tb, 0, stream>>>(W2,   W2T,   4096, 1024);

  // qkv = x @ Wqkv + bqkv -> bf16
  gemm256<<<dim3(3072 / 256, TOKENS / 256), 512, 0, stream>>>(
      xb, WqkvT, bqkv, nullptr, nullptr, qkvb, TOKENS, 3072, 1024, 0);

  attn_kernel<<<TOKENS, 256, 0, stream>>>(qkvb, ctx);

  // y = ctx @ Wo + bo + x -> bf16
  gemm256<<<dim3(1024 / 256, TOKENS / 256), 512, 0, stream>>>(
      ctx, WoT, bo, x, nullptr, ybufb, TOKENS, 1024, 1024, 2);

  ln_kernel<<<TOKENS, 256, 0, stream>>>(ybufb, g1, be1, x1b, nullptr);

  // h = relu(x1 @ W1 + b1) -> bf16
  gemm256<<<dim3(4096 / 256, TOKENS / 256), 512, 0, stream>>>(
      x1b, W1T, b1, nullptr, nullptr, hbuf, TOKENS, 4096, 1024, 1);

  // y2 = h @ W2 + b2 + x1 -> bf16
  gemm256<<<dim3(1024 / 256, TOKENS / 256), 512, 0, stream>>>(
      hbuf, W2T, b2, nullptr, x1b, y2b, TOKENS, 1024, 4096, 3);

  ln_kernel<<<TOKENS, 256, 0, stream>>>(y2b, g2, be2, nullptr, out);
}

// Round 7
// 631.570 us; speedup vs baseline: 1.0631x; 1.0631x over previous
//
#include <hip/hip_runtime.h>
#include <hip/hip_bf16.h>
#include <stdint.h>

using bf16 = __hip_bfloat16;
typedef __bf16 bf16x8 __attribute__((ext_vector_type(8)));
typedef float  f32x4  __attribute__((ext_vector_type(4)));

#define TOKENS 16384
#define DMODEL 1024
#define DFF    4096

// ---------------------------------------------------------------------------
// async global->LDS, 16B per lane. LDS dest = wave-uniform base + lane*16.
// ---------------------------------------------------------------------------
__device__ __forceinline__ void gload_lds16(const void* gptr, void* lptr) {
  __builtin_amdgcn_global_load_lds(
      (const __attribute__((address_space(1))) uint32_t*)gptr,
      (__attribute__((address_space(3))) uint32_t*)lptr,
      16, 0, 0);
}

__device__ __forceinline__ float bfraw2f(unsigned short u) {
  union { unsigned int i; float f; } x;
  x.i = ((unsigned int)u) << 16;
  return x.f;
}

__device__ __forceinline__ unsigned short f2bfraw(float f) {
  union { float f; unsigned int i; } x;
  x.f = f;
  unsigned int lsb = (x.i >> 16) & 1;
  return (unsigned short)((x.i + 0x7fff + lsb) >> 16);  // RNE (finite inputs)
}

// unpack a packed bf16 pair (one uint32) to two floats: 2 VALU ops.
__device__ __forceinline__ float2 bfpair(uint32_t w) {
  union { uint32_t i; float f; } lo, hi;
  lo.i = w << 16;
  hi.i = w & 0xffff0000u;
  return make_float2(lo.f, hi.f);
}

__device__ __forceinline__ uint32_t packbf(float x, float y) {
  return (uint32_t)f2bfraw(x) | ((uint32_t)f2bfraw(y) << 16);
}

// ---------------------------------------------------------------------------
// f32 -> bf16 elementwise convert (x). One float4 per thread.
// ---------------------------------------------------------------------------
__global__ __launch_bounds__(256) void cvt_f32_bf16(
    const float* __restrict__ in, bf16* __restrict__ out, int n4) {
  const int i = blockIdx.x * 256 + threadIdx.x;
  if (i >= n4) return;
  const float4 v = reinterpret_cast<const float4*>(in)[i];
  bf16 o[4] = {__float2bfloat16(v.x), __float2bfloat16(v.y),
               __float2bfloat16(v.z), __float2bfloat16(v.w)};
  reinterpret_cast<uint2*>(out)[i] = *reinterpret_cast<const uint2*>(o);
}

// ---------------------------------------------------------------------------
// Tiled transpose + convert: in[R][C] (f32) -> out[C][R] (bf16).
// ---------------------------------------------------------------------------
__global__ __launch_bounds__(256) void transpose_f32_bf16(
    const float* __restrict__ in, bf16* __restrict__ out, int R, int C) {
  __shared__ float tile[32][33];
  const int bx = blockIdx.x * 32;
  const int by = blockIdx.y * 32;
  const int tx = threadIdx.x;
  const int ty = threadIdx.y;
#pragma unroll
  for (int i = 0; i < 32; i += 8)
    tile[ty + i][tx] = in[(size_t)(by + ty + i) * C + (bx + tx)];
  __syncthreads();
#pragma unroll
  for (int i = 0; i < 32; i += 8)
    out[(size_t)(bx + ty + i) * R + (by + tx)] =
        __float2bfloat16(tile[tx][ty + i]);
}

// ---------------------------------------------------------------------------
// 256x256 8-phase GEMM, SINGLE barrier per phase.  (unchanged — control.)
// ---------------------------------------------------------------------------
__device__ __forceinline__ bf16x8 ldsfrag(const bf16* region, int lrow, int cb) {
  return *reinterpret_cast<const bf16x8*>(
      region + lrow * 64 + (((cb) ^ ((lrow & 7) << 4)) >> 1));
}

__device__ __forceinline__ void read_afrag(
    bf16x8 (&af)[4][2], const bf16* Ar, int wm, int lane) {
  const int lr = lane & 15, cb0 = (lane >> 4) * 16;
#pragma unroll
  for (int mi = 0; mi < 4; ++mi)
#pragma unroll
    for (int ks = 0; ks < 2; ++ks)
      af[mi][ks] = ldsfrag(Ar, wm * 64 + mi * 16 + lr, ks * 64 + cb0);
}

__device__ __forceinline__ void read_bfrag(
    bf16x8 (&bq)[2][2], const bf16* Br, int wn, int lane) {
  const int lr = lane & 15, cb0 = (lane >> 4) * 16;
#pragma unroll
  for (int ni = 0; ni < 2; ++ni)
#pragma unroll
    for (int ks = 0; ks < 2; ++ks)
      bq[ni][ks] = ldsfrag(Br, wn * 32 + ni * 16 + lr, ks * 64 + cb0);
}

template <int MQ, int NQ, int WAIT, bool READ_A>
__device__ __forceinline__ void phase_op(
    f32x4 (&acc)[8][4], bf16x8 (&af)[4][2], const bf16* Ar, const bf16* Br,
    const int wm, const int wn, const int lane,
    const bf16* g0, bf16* l0, const bf16* g1, bf16* l1) {
  if constexpr (READ_A) read_afrag(af, Ar, wm, lane);
  bf16x8 bq[2][2];
  read_bfrag(bq, Br, wn, lane);
  if (g0 != nullptr) { gload_lds16(g0, l0); gload_lds16(g1, l1); }
  if constexpr (WAIT == 4) asm volatile("s_waitcnt vmcnt(4)" ::: "memory");
  if constexpr (WAIT == 0) asm volatile("s_waitcnt vmcnt(0)" ::: "memory");
  asm volatile("s_barrier" ::: "memory");
  __builtin_amdgcn_s_setprio(1);
#pragma unroll
  for (int mi = 0; mi < 4; ++mi)
#pragma unroll
    for (int ni = 0; ni < 2; ++ni)
#pragma unroll
      for (int ks = 0; ks < 2; ++ks)
        acc[MQ * 4 + mi][NQ * 2 + ni] = __builtin_amdgcn_mfma_f32_16x16x32_bf16(
            bq[ni][ks], af[mi][ks], acc[MQ * 4 + mi][NQ * 2 + ni], 0, 0, 0);
  __builtin_amdgcn_s_setprio(0);
  // no trailing barrier: next phase's reads may overlap other waves' MFMAs
}

// stage macros: (tile, half, LDS-region) -> 4 args (gsrc0,ldst0,gsrc1,ldst1)
#define STG_A(tile, h, dst)                                  \
  Ab + offA[h][0] + (size_t)(tile) * 64, (dst) + oe0,        \
  Ab + offA[h][1] + (size_t)(tile) * 64, (dst) + oe1
#define STG_B(tile, q, dst)                                  \
  Bt + offB[q][0] + (size_t)(tile) * 64, (dst) + oe0,        \
  Bt + offB[q][1] + (size_t)(tile) * 64, (dst) + oe1
#define STG_NONE \
  (const bf16*)nullptr, (bf16*)nullptr, (const bf16*)nullptr, (bf16*)nullptr

__global__ __launch_bounds__(512, 2) void gemm256(
    const bf16* __restrict__ Ab, const bf16* __restrict__ Bt,
    const float* __restrict__ bias, const float* __restrict__ resf,
    const bf16* __restrict__ resb, bf16* __restrict__ outb,
    const int M, const int N, const int K, const int epi) {
  union SMem {
    struct { bf16 A[2][2][8192]; bf16 B[2][2][8192]; } p;  // 128 KiB
    bf16 C[256 * 256];                                     // 128 KiB
  };
  __shared__ alignas(16) SMem sm;

  const int t    = threadIdx.x;
  const int wave = t >> 6;
  const int lane = t & 63;
  const int wm = wave >> 2;   // 0..1  (M wave index, 128 rows each)
  const int wn = wave & 3;    // 0..3  (N wave index, 64 cols each)

  // XCD-aware bijective swizzle (all grids here have nwg % 8 == 0)
  const int gx  = gridDim.x;
  const int nwg = gx * (int)gridDim.y;
  const int bid = (int)blockIdx.y * gx + (int)blockIdx.x;
  const int cpx = nwg >> 3;
  const int swz = (bid & 7) * cpx + (bid >> 3);
  const int m_base = (swz / gx) * 256;
  const int n_base = (swz % gx) * 256;

  // staging source offsets (pre-swizzled global columns so gload_lds' linear
  // LDS writes land XOR-swizzled; readers apply the same XOR)
  const int tr8 = t >> 3;                                // 0..63
  const int ksw = ((t & 7) * 8) ^ ((tr8 & 7) * 8);       // swizzled k within BK
  uint32_t offA[2][2], offB[2][2];                       // [half][L]
#pragma unroll
  for (int h = 0; h < 2; ++h)
#pragma unroll
    for (int L = 0; L < 2; ++L) {
      offA[h][L] =
          (uint32_t)(m_base + L * 128 + h * 64 + tr8) * (uint32_t)K + ksw;
      offB[h][L] =
          (uint32_t)(n_base + (L * 2 + (t >> 8)) * 64 + h * 32 + (tr8 & 31)) *
              (uint32_t)K + ksw;
    }
  const int oe0 = t * 8;         // LDS element offset, load L=0
  const int oe1 = 4096 + t * 8;  // load L=1

  bf16* const A00 = sm.p.A[0][0]; bf16* const A01 = sm.p.A[0][1];
  bf16* const A10 = sm.p.A[1][0]; bf16* const A11 = sm.p.A[1][1];
  bf16* const B00 = sm.p.B[0][0]; bf16* const B01 = sm.p.B[0][1];
  bf16* const B10 = sm.p.B[1][0]; bf16* const B11 = sm.p.B[1][1];

  f32x4 acc[8][4] = {};
  bf16x8 af[4][2];  // pair-shared A fragment file (read at odd phases)

  // prologue: T0 {A0,B0,A1,B1} (buf0) + T1 {A0,B0} (buf1) = 12 loads;
  // vmcnt(4) retires all of T0, leaves T1.A0/B0 in flight.
  gload_lds16(Ab + offA[0][0], A00 + oe0);
  gload_lds16(Ab + offA[0][1], A00 + oe1);
  gload_lds16(Bt + offB[0][0], B00 + oe0);
  gload_lds16(Bt + offB[0][1], B00 + oe1);
  gload_lds16(Ab + offA[1][0], A01 + oe0);
  gload_lds16(Ab + offA[1][1], A01 + oe1);
  gload_lds16(Bt + offB[1][0], B01 + oe0);
  gload_lds16(Bt + offB[1][1], B01 + oe1);
  gload_lds16(Ab + offA[0][0] + 64, A10 + oe0);
  gload_lds16(Ab + offA[0][1] + 64, A10 + oe1);
  gload_lds16(Bt + offB[0][0] + 64, B10 + oe0);
  gload_lds16(Bt + offB[0][1] + 64, B10 + oe1);
  asm volatile("s_waitcnt vmcnt(4)" ::: "memory");
  asm volatile("s_barrier" ::: "memory");

  // main loop: iteration computes tiles T=2i (buf0, P1-4) and T+1 (buf1, P5-8)
  // stage ledger (region is dead when staged; waits retire the needed tile):
  //  P1:(T+1).A1->A11  P2:(T+1).B1->B11  P3:(T+2).A0->A00  P4:(T+2).B0->B00 +vmcnt(4)
  //  P5:(T+2).A1->A01  P6:(T+2).B1->B01  P7:(T+3).A0->A10  P8:(T+3).B0->B10 +vmcnt(4)
  const int niter = K >> 7;  // K/128
  for (int i = 0; i < niter - 1; ++i) {
    const int T = 2 * i;
    phase_op<0, 0, -1, true >(acc, af, A00, B00, wm, wn, lane, STG_A(T + 1, 1, A11));
    phase_op<0, 1, -1, false>(acc, af, A00, B01, wm, wn, lane, STG_B(T + 1, 1, B11));
    phase_op<1, 0, -1, true >(acc, af, A01, B00, wm, wn, lane, STG_A(T + 2, 0, A00));
    phase_op<1, 1,  4, false>(acc, af, A01, B01, wm, wn, lane, STG_B(T + 2, 0, B00));
    phase_op<0, 0, -1, true >(acc, af, A10, B10, wm, wn, lane, STG_A(T + 2, 1, A01));
    phase_op<0, 1, -1, false>(acc, af, A10, B11, wm, wn, lane, STG_B(T + 2, 1, B01));
    phase_op<1, 0, -1, true >(acc, af, A11, B10, wm, wn, lane, STG_A(T + 3, 0, A10));
    phase_op<1, 1,  4, false>(acc, af, A11, B11, wm, wn, lane, STG_B(T + 3, 0, B10));
  }
  {  // last iteration: finish staging T+1, drain at P4, no further prefetch
    const int T = 2 * (niter - 1);
    phase_op<0, 0, -1, true >(acc, af, A00, B00, wm, wn, lane, STG_A(T + 1, 1, A11));
    phase_op<0, 1, -1, false>(acc, af, A00, B01, wm, wn, lane, STG_B(T + 1, 1, B11));
    phase_op<1, 0, -1, true >(acc, af, A01, B00, wm, wn, lane, STG_NONE);
    phase_op<1, 1,  0, false>(acc, af, A01, B01, wm, wn, lane, STG_NONE);
    phase_op<0, 0, -1, true >(acc, af, A10, B10, wm, wn, lane, STG_NONE);
    phase_op<0, 1, -1, false>(acc, af, A10, B11, wm, wn, lane, STG_NONE);
    phase_op<1, 0, -1, true >(acc, af, A11, B10, wm, wn, lane, STG_NONE);
    phase_op<1, 1, -1, false>(acc, af, A11, B11, wm, wn, lane, STG_NONE);
  }

  __syncthreads();  // full drain; LDS now reused as swizzled C-stage

  // stage C tile (bias/relu in-register), XOR-swizzled cols (stride 256)
  const int lr = lane & 15;
  const int g4 = lane >> 4;
#pragma unroll
  for (int nj = 0; nj < 4; ++nj) {
    const int cb = wn * 64 + nj * 16 + g4 * 4;
    const float4 bv4 = *reinterpret_cast<const float4*>(&bias[n_base + cb]);
#pragma unroll
    for (int mi = 0; mi < 8; ++mi) {
      const int row = wm * 128 + mi * 16 + lr;
      const f32x4 a = acc[mi][nj];
      float v0 = a[0] + bv4.x, v1 = a[1] + bv4.y;
      float v2 = a[2] + bv4.z, v3 = a[3] + bv4.w;
      if (epi == 1) {
        v0 = fmaxf(v0, 0.f); v1 = fmaxf(v1, 0.f);
        v2 = fmaxf(v2, 0.f); v3 = fmaxf(v3, 0.f);
      }
      ushort4 pk = {f2bfraw(v0), f2bfraw(v1), f2bfraw(v2), f2bfraw(v3)};
      *reinterpret_cast<ushort4*>(
          &sm.C[row * 256 + (cb ^ ((row & 7) << 3))]) = pk;
    }
  }
  __syncthreads();

  // coalesced flush: 16 rows/pass, 16B per lane (512B per row)
#pragma unroll
  for (int pass = 0; pass < 16; ++pass) {
    const int row = pass * 16 + (t >> 5);
    const int fce = (t & 31) * 8;
    const uint4 raw = *reinterpret_cast<const uint4*>(
        &sm.C[row * 256 + (fce ^ ((row & 7) << 3))]);
    const size_t gidx = (size_t)(m_base + row) * N + n_base + fce;
    if (epi <= 1) {
      *reinterpret_cast<uint4*>(&outb[gidx]) = raw;
    } else {
      const unsigned short* u = reinterpret_cast<const unsigned short*>(&raw);
      float v[8];
#pragma unroll
      for (int j = 0; j < 8; ++j) v[j] = bfraw2f(u[j]);
      if (epi == 2) {
        const float4 r0 = *reinterpret_cast<const float4*>(&resf[gidx]);
        const float4 r1 = *reinterpret_cast<const float4*>(&resf[gidx + 4]);
        v[0] += r0.x; v[1] += r0.y; v[2] += r0.z; v[3] += r0.w;
        v[4] += r1.x; v[5] += r1.y; v[6] += r1.z; v[7] += r1.w;
      } else {
        const uint4 rb = *reinterpret_cast<const uint4*>(&resb[gidx]);
        const unsigned short* ru = reinterpret_cast<const unsigned short*>(&rb);
#pragma unroll
        for (int j = 0; j < 8; ++j) v[j] += bfraw2f(ru[j]);
      }
      ushort4 lo = {f2bfraw(v[0]), f2bfraw(v[1]), f2bfraw(v[2]), f2bfraw(v[3])};
      ushort4 hi = {f2bfraw(v[4]), f2bfraw(v[5]), f2bfraw(v[6]), f2bfraw(v[7])};
      uint4 o;
      o.x = *reinterpret_cast<const uint32_t*>(&lo.x);
      o.y = *reinterpret_cast<const uint32_t*>(&lo.z);
      o.z = *reinterpret_cast<const uint32_t*>(&hi.x);
      o.w = *reinterpret_cast<const uint32_t*>(&hi.z);
      *reinterpret_cast<uint4*>(&outb[gidx]) = o;
    }
  }
}

// ---------------------------------------------------------------------------
// Per-token head-mixing attention, register-tiled: 1 wave per token,
// 4 tokens per 256-thread block.
// qkv row (3072 bf16) staged once into LDS rows[16][216] (stride 432 B:
// 16B-aligned, bank aliasing <=2-way = free). Each lane computes a 2x2
// score tile (h pair = lane>>3, g pair = lane&7): 8 chunk-iters x 4
// ds_read_b128 -> 32 reads/token vs 512 b32 before. Softmax in-register
// (shfl_xor 1,2,4 within the 8-lane g-group). PV: lane owns 2 h-rows x
// 8 d-cols; p redistributed via pw[16][18] (pad 18 -> conflict-free).
// ---------------------------------------------------------------------------
__global__ __launch_bounds__(256) void attn_kernel(
    const bf16* __restrict__ qkv, bf16* __restrict__ ctx) {
  __shared__ alignas(16) unsigned short rows[4][16][216];  // 27648 B
  __shared__ float pw[4][16][18];                          //  4608 B
  const int wv   = threadIdx.x >> 6;
  const int lane = threadIdx.x & 63;
  const int tok  = blockIdx.x * 4 + wv;

  // stage: 384 coalesced 16B chunks -> padded rows (row = chunk/24)
  const unsigned short* src =
      reinterpret_cast<const unsigned short*>(qkv) + (size_t)tok * 3072;
#pragma unroll
  for (int j = 0; j < 6; ++j) {
    const int cid = j * 64 + lane;
    const int r = cid / 24, cc = cid - r * 24;
    const uint4 d = *reinterpret_cast<const uint4*>(src + cid * 8);
    *reinterpret_cast<uint4*>(&rows[wv][r][cc * 8]) = d;
  }
  __syncthreads();

  const int h2 = lane >> 3;  // h pair: rows 2h2, 2h2+1
  const int g2 = lane & 7;   // g pair: rows 2g2, 2g2+1
  float s00 = 0.f, s01 = 0.f, s10 = 0.f, s11 = 0.f;
#pragma unroll
  for (int c = 0; c < 8; ++c) {
    const uint4 qa = *reinterpret_cast<const uint4*>(&rows[wv][2 * h2][c * 8]);
    const uint4 qb = *reinterpret_cast<const uint4*>(&rows[wv][2 * h2 + 1][c * 8]);
    const uint4 ka = *reinterpret_cast<const uint4*>(&rows[wv][2 * g2][64 + c * 8]);
    const uint4 kb = *reinterpret_cast<const uint4*>(&rows[wv][2 * g2 + 1][64 + c * 8]);
    const uint32_t* qaw = reinterpret_cast<const uint32_t*>(&qa);
    const uint32_t* qbw = reinterpret_cast<const uint32_t*>(&qb);
    const uint32_t* kaw = reinterpret_cast<const uint32_t*>(&ka);
    const uint32_t* kbw = reinterpret_cast<const uint32_t*>(&kb);
#pragma unroll
    for (int w = 0; w < 4; ++w) {
      const float2 fqa = bfpair(qaw[w]), fqb = bfpair(qbw[w]);
      const float2 fka = bfpair(kaw[w]), fkb = bfpair(kbw[w]);
      s00 += fqa.x * fka.x; s00 += fqa.y * fka.y;
      s01 += fqa.x * fkb.x; s01 += fqa.y * fkb.y;
      s10 += fqb.x * fka.x; s10 += fqb.y * fka.y;
      s11 += fqb.x * fkb.x; s11 += fqb.y * fkb.y;
    }
  }
  s00 *= 0.125f; s01 *= 0.125f; s10 *= 0.125f; s11 *= 0.125f;

  // softmax over g (per h-row): reduce across the 8-lane g-group
  float m0 = fmaxf(s00, s01), m1 = fmaxf(s10, s11);
#pragma unroll
  for (int off = 1; off < 8; off <<= 1) {
    m0 = fmaxf(m0, __shfl_xor(m0, off));
    m1 = fmaxf(m1, __shfl_xor(m1, off));
  }
  const float e00 = __expf(s00 - m0), e01 = __expf(s01 - m0);
  const float e10 = __expf(s10 - m1), e11 = __expf(s11 - m1);
  float t0 = e00 + e01, t1 = e10 + e11;
#pragma unroll
  for (int off = 1; off < 8; off <<= 1) {
    t0 += __shfl_xor(t0, off);
    t1 += __shfl_xor(t1, off);
  }
  const float r0 = 1.f / t0, r1 = 1.f / t1;
  pw[wv][2 * h2][2 * g2]         = e00 * r0;
  pw[wv][2 * h2][2 * g2 + 1]     = e01 * r0;
  pw[wv][2 * h2 + 1][2 * g2]     = e10 * r1;
  pw[wv][2 * h2 + 1][2 * g2 + 1] = e11 * r1;
  __syncthreads();

  // PV: lane owns h rows {2h2, 2h2+1}, d cols dc*8..dc*8+7
  const int dc = lane & 7;
  float a0[8] = {0.f, 0.f, 0.f, 0.f, 0.f, 0.f, 0.f, 0.f};
  float a1[8] = {0.f, 0.f, 0.f, 0.f, 0.f, 0.f, 0.f, 0.f};
#pragma unroll
  for (int g = 0; g < 16; ++g) {
    const float w0 = pw[wv][2 * h2][g];
    const float w1 = pw[wv][2 * h2 + 1][g];
    const uint4 v = *reinterpret_cast<const uint4*>(&rows[wv][g][128 + dc * 8]);
    const uint32_t* vw = reinterpret_cast<const uint32_t*>(&v);
#pragma unroll
    for (int w = 0; w < 4; ++w) {
      const float2 fv = bfpair(vw[w]);
      a0[2 * w]     += w0 * fv.x;  a0[2 * w + 1] += w0 * fv.y;
      a1[2 * w]     += w1 * fv.x;  a1[2 * w + 1] += w1 * fv.y;
    }
  }
  uint4 o0, o1;
  o0.x = packbf(a0[0], a0[1]); o0.y = packbf(a0[2], a0[3]);
  o0.z = packbf(a0[4], a0[5]); o0.w = packbf(a0[6], a0[7]);
  o1.x = packbf(a1[0], a1[1]); o1.y = packbf(a1[2], a1[3]);
  o1.z = packbf(a1[4], a1[5]); o1.w = packbf(a1[6], a1[7]);
  unsigned short* dst =
      reinterpret_cast<unsigned short*>(ctx) + (size_t)tok * 1024;
  *reinterpret_cast<uint4*>(dst + (2 * h2) * 64 + dc * 8)     = o0;
  *reinterpret_cast<uint4*>(dst + (2 * h2 + 1) * 64 + dc * 8) = o1;
}

// ---------------------------------------------------------------------------
// LayerNorm over 1024, bf16 input, f32 gamma/beta.
// ---------------------------------------------------------------------------
__global__ __launch_bounds__(256) void ln_kernel(
    const bf16* __restrict__ y, const float* __restrict__ gamma,
    const float* __restrict__ beta, bf16* __restrict__ outb,
    float* __restrict__ outf) {
  const int row = blockIdx.x;
  const int t = threadIdx.x;
  const uint2 raw =
      reinterpret_cast<const uint2*>(y + (size_t)row * 1024)[t];
  float f0 = bfraw2f((unsigned short)(raw.x & 0xffff));
  float f1 = bfraw2f((unsigned short)(raw.x >> 16));
  float f2 = bfraw2f((unsigned short)(raw.y & 0xffff));
  float f3 = bfraw2f((unsigned short)(raw.y >> 16));
  float s  = f0 + f1 + f2 + f3;
  float ss = f0 * f0 + f1 * f1 + f2 * f2 + f3 * f3;
#pragma unroll
  for (int off = 32; off > 0; off >>= 1) {
    s  += __shfl_down(s, off);
    ss += __shfl_down(ss, off);
  }
  __shared__ float red[8];
  const int wave = t >> 6, lane = t & 63;
  if (lane == 0) { red[wave] = s; red[wave + 4] = ss; }
  __syncthreads();
  s  = red[0] + red[1] + red[2] + red[3];
  ss = red[4] + red[5] + red[6] + red[7];
  const float mu  = s * (1.0f / 1024.0f);
  const float var = ss * (1.0f / 1024.0f) - mu * mu;
  const float inv = rsqrtf(var + 1e-5f);
  const int c = t * 4;
  const float r0 = (f0 - mu) * inv * gamma[c + 0] + beta[c + 0];
  const float r1 = (f1 - mu) * inv * gamma[c + 1] + beta[c + 1];
  const float r2 = (f2 - mu) * inv * gamma[c + 2] + beta[c + 2];
  const float r3 = (f3 - mu) * inv * gamma[c + 3] + beta[c + 3];
  if (outf != nullptr) {
    float4 o4 = {r0, r1, r2, r3};
    reinterpret_cast<float4*>(outf + (size_t)row * 1024)[t] = o4;
  } else {
    bf16 o[4] = {__float2bfloat16(r0), __float2bfloat16(r1),
                 __float2bfloat16(r2), __float2bfloat16(r3)};
    *reinterpret_cast<uint2*>(outb + (size_t)row * 1024 + c) =
        *reinterpret_cast<const uint2*>(o);
  }
}

// ---------------------------------------------------------------------------
extern "C" void kernel_launch(void* const* d_in, const int* in_sizes, int n_in,
                              void* d_out, int out_size, void* d_ws, size_t ws_size,
                              hipStream_t stream) {
  const float* x    = (const float*)d_in[0];
  const float* Wqkv = (const float*)d_in[1];
  const float* bqkv = (const float*)d_in[2];
  const float* Wo   = (const float*)d_in[3];
  const float* bo   = (const float*)d_in[4];
  const float* W1   = (const float*)d_in[5];
  const float* b1   = (const float*)d_in[6];
  const float* W2   = (const float*)d_in[7];
  const float* b2   = (const float*)d_in[8];
  const float* g1   = (const float*)d_in[9];
  const float* be1  = (const float*)d_in[10];
  const float* g2   = (const float*)d_in[11];
  const float* be2  = (const float*)d_in[12];
  float* out = (float*)d_out;

  // Workspace layout (overlays annotated). Total ~226 MB.
  char* p = (char*)d_ws;
  bf16* regA  = (bf16*)p;  p += (size_t)TOKENS * 1024 * 2;
  bf16* qkvb  = (bf16*)p;
  bf16* hbuf  = qkvb;
  p += (size_t)TOKENS * 3072 * 2;
  bf16* ybufb = (bf16*)p;  p += (size_t)TOKENS * 1024 * 2;
  bf16* x1b   = (bf16*)p;  p += (size_t)TOKENS * 1024 * 2;
  bf16* WqkvT = (bf16*)p;  p += (size_t)3072 * 1024 * 2;
  bf16* WoT   = (bf16*)p;  p += (size_t)1024 * 1024 * 2;
  bf16* W1T   = (bf16*)p;  p += (size_t)4096 * 1024 * 2;
  bf16* W2T   = (bf16*)p;  p += (size_t)1024 * 4096 * 2;

  bf16* xb  = regA;
  bf16* ctx = regA;
  bf16* y2b = regA;

  cvt_f32_bf16<<<(TOKENS * 1024 / 4 + 255) / 256, 256, 0, stream>>>(
      x, xb, TOKENS * 1024 / 4);

  const dim3 tb(32, 8);
  transpose_f32_bf16<<<dim3(3072 / 32, 1024 / 32), tb, 0, stream>>>(Wqkv, WqkvT, 1024, 3072);
  transpose_f32_bf16<<<dim3(1024 / 32, 1024 / 32), tb, 0, stream>>>(Wo,   WoT,   1024, 1024);
  transpose_f32_bf16<<<dim3(4096 / 32, 1024 / 32), tb, 0, stream>>>(W1,   W1T,   1024, 4096);
  transpose_f32_bf16<<<dim3(1024 / 32, 4096 / 32), tb, 0, stream>>>(W2,   W2T,   4096, 1024);

  // qkv = x @ Wqkv + bqkv -> bf16
  gemm256<<<dim3(3072 / 256, TOKENS / 256), 512, 0, stream>>>(
      xb, WqkvT, bqkv, nullptr, nullptr, qkvb, TOKENS, 3072, 1024, 0);

  attn_kernel<<<TOKENS / 4, 256, 0, stream>>>(qkvb, ctx);

  // y = ctx @ Wo + bo + x -> bf16
  gemm256<<<dim3(1024 / 256, TOKENS / 256), 512, 0, stream>>>(
      ctx, WoT, bo, x, nullptr, ybufb, TOKENS, 1024, 1024, 2);

  ln_kernel<<<TOKENS, 256, 0, stream>>>(ybufb, g1, be1, x1b, nullptr);

  // h = relu(x1 @ W1 + b1) -> bf16
  gemm256<<<dim3(4096 / 256, TOKENS / 256), 512, 0, stream>>>(
      x1b, W1T, b1, nullptr, nullptr, hbuf, TOKENS, 4096, 1024, 1);

  // y2 = h @ W2 + b2 + x1 -> bf16
  gemm256<<<dim3(1024 / 256, TOKENS / 256), 512, 0, stream>>>(
      hbuf, W2T, b2, nullptr, x1b, y2b, TOKENS, 1024, 4096, 3);

  ln_kernel<<<TOKENS, 256, 0, stream>>>(y2b, g2, be2, nullptr, out);
}